// Round 1
// 913.591 us; speedup vs baseline: 1.3445x; 1.3445x over previous
//
#include <hip/hip_runtime.h>
#include <cstdint>
#include <cstddef>

typedef __attribute__((ext_vector_type(8))) __bf16 bf16x8;
typedef __attribute__((ext_vector_type(4))) float  f32x4;

static_assert(sizeof(bf16x8) == 16, "bf16x8 must be 16B");

__device__ __forceinline__ float fast_tanh(float x) {
    // tanh(x) = 1 - 2/(e^{2x}+1); v_exp + v_rcp. Handles +-inf correctly.
    float e = __expf(2.0f * x);
    return 1.0f - 2.0f * __builtin_amdgcn_rcpf(e + 1.0f);
}

// agent-scope (cross-XCD coherent) 16B load as 2x u64 atomics: bypasses L1/L2
// so ping-pong H buffers never serve stale lines; compiler handles waitcnts.
__device__ __forceinline__ bf16x8 load_h(const __bf16* p) {
    union { bf16x8 v; unsigned long long q[2]; } u;
    unsigned long long* qp = (unsigned long long*)p;
    u.q[0] = __hip_atomic_load(qp, __ATOMIC_RELAXED, __HIP_MEMORY_SCOPE_AGENT);
    u.q[1] = __hip_atomic_load(qp + 1, __ATOMIC_RELAXED, __HIP_MEMORY_SCOPE_AGENT);
    return u.v;
}

// ---- K0a: bias = b_ih + b_hh ; block 0 zeroes the group-barrier counters ----
__global__ void k_bias(const float* __restrict__ b_ih, const float* __restrict__ b_hh,
                       float* __restrict__ bias, int* __restrict__ cnt) {
    int i = blockIdx.x * 256 + threadIdx.x;  // grid 4
    bias[i] = b_ih[i] + b_hh[i];
    if (blockIdx.x == 0) cnt[threadIdx.x] = 0;  // 256 ints (16 counters, 64B stride)
}

// ---- K0b: W_hh fp32 -> bf16 pre-shuffled into MFMA B-fragment order ----
// Ws[(((t*32 + c)*64) + L)*8 + j] = W[t*16 + (L&15)][c*32 + (L>>4)*8 + j]
__global__ void k_shufw(const float* __restrict__ W, __bf16* __restrict__ Ws) {
    int id = blockIdx.x * 256 + threadIdx.x;  // grid 512 -> 131072 = 64t*32c*64L
    int t = id >> 11;
    int c = (id >> 6) & 31;
    int L = id & 63;
    const float* src = W + (size_t)(t * 16 + (L & 15)) * 1024 + c * 32 + (L >> 4) * 8;
    __bf16* dst = Ws + (size_t)id * 8;
#pragma unroll
    for (int j = 0; j < 8; ++j) dst[j] = (__bf16)src[j];
}

// ---- K1a: M = Bw @ Bw^T (64x64). 64 blocks, block i computes row i. ----
__global__ void k_gram(const float* __restrict__ Bw, float* __restrict__ M) {
    int i = blockIdx.x;                 // 64 blocks
    int j = threadIdx.x >> 2;           // 64 cols
    int q = threadIdx.x & 3;            // K-quarter
    const float4* a = (const float4*)(Bw + (size_t)i * 1024) + q * 64;
    const float4* b = (const float4*)(Bw + (size_t)j * 1024) + q * 64;
    float acc = 0.f;
#pragma unroll 8
    for (int t = 0; t < 64; ++t) {
        float4 av = a[t], bv = b[t];
        acc += av.x * bv.x + av.y * bv.y + av.z * bv.z + av.w * bv.w;
    }
    acc += __shfl_xor(acc, 1);
    acc += __shfl_xor(acc, 2);
    if (q == 0) M[i * 64 + j] = acc;
}

// ---- K1b: Minv via Newton-Schulz, conflict-free LDS version ----
// 1024 threads: lane i = tid&63 (coalesced dim), wave w = tid>>6 owns cols w*4..+4.
// Exploits symmetry of M and X: column reads become coalesced row reads; the
// per-(k,j) operand reads are wave-uniform (LDS broadcast, free).
__global__ __launch_bounds__(1024) void k_newton(const float* __restrict__ M,
                                                 float* __restrict__ Minv) {
    __shared__ float Mm[4096];
    __shared__ float X[4096];
    __shared__ float Tt[4096];   // T = M@X stored transposed: Tt[j*64+i] = T[i][j]
    const int tid = threadIdx.x;
    const int i = tid & 63;
    const int w = tid >> 6;      // 16 waves, cols w*4 + jj
    for (int p = tid; p < 4096; p += 1024) {
        Mm[p] = M[p];
        int r = p >> 6, c2 = p & 63;
        X[p] = (r == c2) ? 0.941f : 0.0f;   // spectrum of M in [0.5625,1.5625]
    }
    __syncthreads();
    for (int it = 0; it < 6; ++it) {
        float r[4] = {0.f, 0.f, 0.f, 0.f};
        for (int kk = 0; kk < 64; ++kk) {
            float mv = Mm[(kk << 6) + i];                       // M[i][kk] (sym), coalesced
            float4 x4 = *(const float4*)&X[(kk << 6) + (w << 2)]; // X[kk][j], broadcast
            r[0] += mv * x4.x; r[1] += mv * x4.y; r[2] += mv * x4.z; r[3] += mv * x4.w;
        }
#pragma unroll
        for (int jj = 0; jj < 4; ++jj) Tt[(((w << 2) + jj) << 6) + i] = r[jj];
        __syncthreads();
        // Xnew[i][j] = 2X[i][j] - sum_k X[i][k] T[k][j]; store transposed (Xnew sym)
        float r2[4];
#pragma unroll
        for (int jj = 0; jj < 4; ++jj) r2[jj] = 2.f * X[(((w << 2) + jj) << 6) + i];
        for (int kq = 0; kq < 16; ++kq) {
            float xv0 = X[((kq * 4 + 0) << 6) + i];
            float xv1 = X[((kq * 4 + 1) << 6) + i];
            float xv2 = X[((kq * 4 + 2) << 6) + i];
            float xv3 = X[((kq * 4 + 3) << 6) + i];
#pragma unroll
            for (int jj = 0; jj < 4; ++jj) {
                float4 t4 = *(const float4*)&Tt[(((w << 2) + jj) << 6) + (kq << 2)];
                r2[jj] -= xv0 * t4.x + xv1 * t4.y + xv2 * t4.z + xv3 * t4.w;
            }
        }
        __syncthreads();
#pragma unroll
        for (int jj = 0; jj < 4; ++jj) X[(((w << 2) + jj) << 6) + i] = r2[jj];
        __syncthreads();
    }
    for (int p = tid; p < 4096; p += 1024) Minv[p] = X[p];
}

// ---- K2a: T1 = X_reset @ Minv (Minv symmetric), (1024 x 64) ----
__global__ void k_t1(const float* __restrict__ x, const float* __restrict__ Minv,
                     float* __restrict__ T1) {
    int id = blockIdx.x * 256 + threadIdx.x;  // 256 blocks
    int r = id >> 6, xp = id & 63;
    const float* xr = x + ((size_t)(r >> 4) * 1024 + (size_t)(r & 15) * 64) * 64;
    const float* mr = Minv + (size_t)xp * 64;
    float acc = 0.f;
    for (int t = 0; t < 64; ++t) acc += xr[t] * mr[t];
    T1[id] = acc;
}

// ---- K2b: H0 = T1 @ Bw  (1024 x 1024), row-major bf16 ----
__global__ void k_h0(const float* __restrict__ T1, const float* __restrict__ Bw,
                     __bf16* __restrict__ H0) {
    int r = blockIdx.y;
    int z = blockIdx.x * 256 + threadIdx.x;  // grid (4,1024)
    const float* t1 = T1 + (size_t)r * 64;
    float acc = 0.f;
    for (int xp = 0; xp < 64; ++xp) acc += t1[xp] * Bw[(size_t)xp * 1024 + z];
    H0[(size_t)r * 1024 + z] = (__bf16)acc;
}

// ---- K3 (fallback only): one recurrence step, as in previous session ----
__global__ __launch_bounds__(256) void k_step(
    const __bf16* __restrict__ Hin, const __bf16* __restrict__ Ws,
    const float* __restrict__ bias, __bf16* __restrict__ Hout,
    float* __restrict__ out, int kstep) {
    const int tid = threadIdx.x;
    const int w = tid >> 6;
    const int lane = tid & 63;
    const int row = lane & 15;
    const int quad = lane >> 4;
    const int bm = blockIdx.x, bn = blockIdx.y;

    const __bf16* Arow = Hin + (size_t)(bm * 64 + w * 16 + row) * 1024 + quad * 8;
    const __bf16* B0 = Ws + ((size_t)((bn * 2 + 0) * 32) * 64 + lane) * 8;
    const __bf16* B1 = Ws + ((size_t)((bn * 2 + 1) * 32) * 64 + lane) * 8;

    f32x4 acc0 = {0.f, 0.f, 0.f, 0.f};
    f32x4 acc1 = {0.f, 0.f, 0.f, 0.f};
#pragma unroll 8
    for (int c = 0; c < 32; ++c) {
        bf16x8 a = *(const bf16x8*)(Arow + c * 32);
        bf16x8 b0 = *(const bf16x8*)(B0 + (size_t)c * 512);
        bf16x8 b1 = *(const bf16x8*)(B1 + (size_t)c * 512);
        acc0 = __builtin_amdgcn_mfma_f32_16x16x32_bf16(a, b0, acc0, 0, 0, 0);
        acc1 = __builtin_amdgcn_mfma_f32_16x16x32_bf16(a, b1, acc1, 0, 0, 0);
    }
#pragma unroll
    for (int nt = 0; nt < 2; ++nt) {
        const f32x4 acc = nt ? acc1 : acc0;
        const int col = bn * 32 + nt * 16 + row;
        const float bv = bias[col];
#pragma unroll
        for (int i = 0; i < 4; ++i) {
            const int m = bm * 64 + w * 16 + quad * 4 + i;
            float v = tanhf(acc[i] + bv);
            const int b_ = m >> 4, s_ = m & 15;
            out[((size_t)b_ * 1024 + (size_t)s_ * 64 + kstep) * 1024 + col] = v;
            Hout[(size_t)m * 1024 + col] = (__bf16)v;
        }
    }
}

// ---- K3': persistent cooperative recurrence kernel ----
// Grid 256 x 256thr, exactly 1 block/CU (LDS 128 KB). Block (bm=bid&15, bn=bid>>4)
// owns output tile rows bm*64..+64, cols bn*64..+64 for ALL 64 steps.
// B-slice (4 n-tiles x full K) resident in LDS, loaded ONCE.
// Dependencies only exist within a row-group (the 16 blocks sharing bm): per-group
// monotonic counter barrier. H ping-pong exchanged via agent-scope (sc0/sc1)
// loads/stores -> no cache writeback/invalidate needed, W stays L2/LDS-hot.
__global__ __launch_bounds__(256, 1) void k_persist(
    const __bf16* __restrict__ Ws, const float* __restrict__ bias,
    __bf16* __restrict__ H0, __bf16* __restrict__ H1,
    float* __restrict__ out, int* cnt) {
    __shared__ __bf16 Bs[65536];   // 128 KB: 4 tiles x 32 c x 64 lanes x 8
    const int tid = threadIdx.x;
    const int bid = blockIdx.x;
    const int bm = bid & 15;   // same-XCD-friendly: bid%16 fixes bid%8
    const int bn = bid >> 4;
    const int lane = tid & 63;
    const int w = tid >> 6;
    const int row = lane & 15, quad = lane >> 4;

    {   // stage this block's 128 KB B-slice (tiles 4bn..4bn+3), contiguous copy
        const bf16x8* src = (const bf16x8*)(Ws + ((size_t)bn << 16));
        bf16x8* dst = (bf16x8*)Bs;
#pragma unroll
        for (int it = 0; it < 32; ++it) dst[it * 256 + tid] = src[it * 256 + tid];
    }
    float bv[4];
#pragma unroll
    for (int nt = 0; nt < 4; ++nt) bv[nt] = bias[bn * 64 + nt * 16 + row];
    __syncthreads();

    const size_t aoff = (size_t)(bm * 64 + w * 16 + row) * 1024 + quad * 8;
    int* mycnt = cnt + bm * 16;   // 64B-padded counters

    for (int k = 0; k < 64; ++k) {
        const __bf16* Hin = (k & 1) ? H1 : H0;
        __bf16* Hout = (k & 1) ? H0 : H1;
        const __bf16* A = Hin + aoff;
        const bf16x8* Bl = (const bf16x8*)Bs + lane;

        f32x4 acc0 = {0.f, 0.f, 0.f, 0.f};
        f32x4 acc1 = acc0, acc2 = acc0, acc3 = acc0;

        // depth-8 A prefetch to cover LLC latency at 1 wave/SIMD
        bf16x8 a0 = load_h(A + 0 * 32), a1 = load_h(A + 1 * 32),
               a2 = load_h(A + 2 * 32), a3 = load_h(A + 3 * 32),
               a4 = load_h(A + 4 * 32), a5 = load_h(A + 5 * 32),
               a6 = load_h(A + 6 * 32), a7 = load_h(A + 7 * 32);

#define KSTEP(AA, CC)                                                                     \
        acc0 = __builtin_amdgcn_mfma_f32_16x16x32_bf16(AA, Bl[(0 * 32 + (CC)) * 64], acc0, 0, 0, 0); \
        acc1 = __builtin_amdgcn_mfma_f32_16x16x32_bf16(AA, Bl[(1 * 32 + (CC)) * 64], acc1, 0, 0, 0); \
        acc2 = __builtin_amdgcn_mfma_f32_16x16x32_bf16(AA, Bl[(2 * 32 + (CC)) * 64], acc2, 0, 0, 0); \
        acc3 = __builtin_amdgcn_mfma_f32_16x16x32_bf16(AA, Bl[(3 * 32 + (CC)) * 64], acc3, 0, 0, 0);

        for (int c = 0; c < 24; c += 8) {
            bf16x8 n0 = load_h(A + (c + 8) * 32),  n1 = load_h(A + (c + 9) * 32),
                   n2 = load_h(A + (c + 10) * 32), n3 = load_h(A + (c + 11) * 32),
                   n4 = load_h(A + (c + 12) * 32), n5 = load_h(A + (c + 13) * 32),
                   n6 = load_h(A + (c + 14) * 32), n7 = load_h(A + (c + 15) * 32);
            KSTEP(a0, c + 0) KSTEP(a1, c + 1) KSTEP(a2, c + 2) KSTEP(a3, c + 3)
            KSTEP(a4, c + 4) KSTEP(a5, c + 5) KSTEP(a6, c + 6) KSTEP(a7, c + 7)
            a0 = n0; a1 = n1; a2 = n2; a3 = n3; a4 = n4; a5 = n5; a6 = n6; a7 = n7;
        }
        KSTEP(a0, 24) KSTEP(a1, 25) KSTEP(a2, 26) KSTEP(a3, 27)
        KSTEP(a4, 28) KSTEP(a5, 29) KSTEP(a6, 30) KSTEP(a7, 31)
#undef KSTEP

        // epilogue: C/D layout col=lane&15, row=quad*4+reg (verified)
        const int mbase = bm * 64 + w * 16 + quad * 4;
#pragma unroll
        for (int nt = 0; nt < 4; ++nt) {
            const f32x4 acc = nt == 0 ? acc0 : nt == 1 ? acc1 : nt == 2 ? acc2 : acc3;
            const int col = bn * 64 + nt * 16 + row;
            const float bb = bv[nt];
#pragma unroll
            for (int i2 = 0; i2 < 4; ++i2) {
                const int m = mbase + i2;
                const float v = fast_tanh(acc[i2] + bb);
                const int b_ = m >> 4, s_ = m & 15;
                out[((size_t)b_ * 1024 + (size_t)s_ * 64 + k) * 1024 + col] = v;
                if (k < 63) {
                    union { __bf16 h; unsigned short s; } cv;
                    cv.h = (__bf16)v;
                    __hip_atomic_store((unsigned short*)(Hout + (size_t)m * 1024 + col),
                                       cv.s, __ATOMIC_RELAXED, __HIP_MEMORY_SCOPE_AGENT);
                }
            }
        }

        __syncthreads();   // drains vmcnt: all H stores acked at coherence point
        if (k < 63) {
            if (tid == 0) {
                __hip_atomic_fetch_add(mycnt, 1, __ATOMIC_RELAXED, __HIP_MEMORY_SCOPE_AGENT);
                const int target = (k + 1) * 16;   // monotonic: no reset race
                while (__hip_atomic_load(mycnt, __ATOMIC_RELAXED, __HIP_MEMORY_SCOPE_AGENT) < target)
                    __builtin_amdgcn_s_sleep(1);
            }
            __syncthreads();
        }
    }
}

extern "C" void kernel_launch(void* const* d_in, const int* in_sizes, int n_in,
                              void* d_out, int out_size, void* d_ws, size_t ws_size,
                              hipStream_t stream) {
    const float* x = (const float*)d_in[0];     // (64,1024,64)
    const float* Bw = (const float*)d_in[1];    // (64,1024)
    const float* W_hh = (const float*)d_in[2];  // (1024,1024)
    const float* b_ih = (const float*)d_in[3];  // (1024,)
    const float* b_hh = (const float*)d_in[4];  // (1024,)
    float* out = (float*)d_out;                 // (64,1024,1024)
    uint8_t* ws = (uint8_t*)d_ws;

    __bf16* Ws = (__bf16*)(ws);                         // 2 MB (shuffled W)
    __bf16* H0 = (__bf16*)(ws + (2ull << 20));          // 2 MB
    __bf16* H1 = (__bf16*)(ws + (4ull << 20));          // 2 MB
    float* bias = (float*)(ws + (6ull << 20));          // 4 KB
    float* Mg = (float*)(ws + (6ull << 20) + 4096);     // 16 KB
    float* Minv = (float*)(ws + (6ull << 20) + 20480);  // 16 KB
    float* T1 = (float*)(ws + (6ull << 20) + 36864);    // 256 KB
    int* cnt = (int*)(ws + (6ull << 20) + 36864 + 262144);  // 1 KB barrier counters

    hipLaunchKernelGGL(k_bias, dim3(4), dim3(256), 0, stream, b_ih, b_hh, bias, cnt);
    hipLaunchKernelGGL(k_shufw, dim3(512), dim3(256), 0, stream, W_hh, Ws);
    hipLaunchKernelGGL(k_gram, dim3(64), dim3(256), 0, stream, Bw, Mg);
    hipLaunchKernelGGL(k_newton, dim3(1), dim3(1024), 0, stream, Mg, Minv);
    hipLaunchKernelGGL(k_t1, dim3(256), dim3(256), 0, stream, x, Minv, T1);
    hipLaunchKernelGGL(k_h0, dim3(4, 1024), dim3(256), 0, stream, T1, Bw, H0);

    const __bf16* Wsp = Ws;
    const float* biasp = bias;
    __bf16* h0p = H0;
    __bf16* h1p = H1;
    float* outp = out;
    int* cntp = cnt;
    void* kargs[] = {&Wsp, &biasp, &h0p, &h1p, &outp, &cntp};
    hipError_t err = hipLaunchCooperativeKernel((void*)k_persist, dim3(256), dim3(256),
                                                kargs, 0, stream);
    if (err != hipSuccess) {
        // fallback: previous-session 64-launch path
        __bf16* bufs[2] = {H0, H1};
        for (int k = 0; k < 64; ++k) {
            hipLaunchKernelGGL(k_step, dim3(16, 32), dim3(256), 0, stream,
                               bufs[k & 1], Ws, bias, bufs[(k + 1) & 1], out, k);
        }
    }
}